// Round 1
// baseline (376.989 us; speedup 1.0000x reference)
//
#include <hip/hip_runtime.h>

typedef short bf16x8 __attribute__((ext_vector_type(8)));
typedef float f32x4 __attribute__((ext_vector_type(4)));

__device__ __forceinline__ unsigned short f2bf(float f) {
  unsigned x = __float_as_uint(f);
  return (unsigned short)((x + 0x7fffu + ((x >> 16) & 1u)) >> 16);  // RNE
}

// H[i] = bf16(relu(sum_z Hp[z][i] + b1[i&8191]));  4 elems/thread, 2048 blocks
__global__ __launch_bounds__(256)
void reduce1_relu_bf16(const float* __restrict__ hp, const float* __restrict__ b1,
                       unsigned short* __restrict__ hbf) {
  const size_t i = ((size_t)blockIdx.x * 256 + threadIdx.x) * 4;
  f32x4 a = *(const f32x4*)(hp + i);
#pragma unroll
  for (int z = 1; z < 4; ++z)
    a += *(const f32x4*)(hp + (size_t)z * 2097152 + i);
  a += *(const f32x4*)(b1 + (i & 8191));
  union { unsigned short u[4]; int2 v; } t;
#pragma unroll
  for (int j = 0; j < 4; ++j) t.u[j] = f2bf(fmaxf(a[j], 0.f));
  *(int2*)(hbf + i) = t.v;
}

// out[i] = sum_z Op[z][i] + b2[i&4095];  4 elems/thread, 1024 blocks
__global__ __launch_bounds__(256)
void reduce2_bias(const float* __restrict__ op, const float* __restrict__ b2,
                  float* __restrict__ out) {
  const size_t i = ((size_t)blockIdx.x * 256 + threadIdx.x) * 4;
  f32x4 a = *(const f32x4*)(op + i);
#pragma unroll
  for (int z = 1; z < 8; ++z)
    a += *(const f32x4*)(op + (size_t)z * 1048576 + i);
  a += *(const f32x4*)(b2 + (i & 4095));
  *(f32x4*)(out + i) = a;
}

// A [M x K] row-major (fp32, or bf16 when ABF16), W [K x N] fp32 row-major.
// Block tile BM=128, BN=64, BK=64; 256 thr = 4 waves 2x2.
// Mask: N-col-block sj (width CW) live for K in [0, (sj+1)*KROW).
// Split-K: block z handles iter range [z*nIter/KS, (z+1)*nIter/KS); each z
// writes a PRIVATE partial slice part[z][256][N] with plain stores (no
// atomics). Empty ranges zero-fill their tile so the reduce can sum all KS
// slices unconditionally. blockIdx.x is reversed so heavy (high-sj) tiles
// dispatch first (LPT scheduling for the triangular imbalance).
template<int KROW, int CW, int KS, bool ABF16>
__global__ __launch_bounds__(256, 3)
void gemm_sk(const void* __restrict__ Av, const float* __restrict__ W,
             float* __restrict__ part, int K, int N)
{
  __shared__ unsigned short Xs[128 * 72];  // [m][k], +8 pad
  __shared__ unsigned short Ws[64 * 72];   // [n][k ^ ((n>>3)<<3)], +8 pad

  const int xr = (int)gridDim.x - 1 - (int)blockIdx.x;   // heavy first
  const int n0 = xr * 64;
  const int m0 = blockIdx.y * 128;
  const int nIter = ((n0 / CW) + 1) * (KROW / 64);  // live BK-iters for tile
  const int i0 = ((int)blockIdx.z) * nIter / KS;
  const int i1 = ((int)blockIdx.z + 1) * nIter / KS;

  float* po = part + (size_t)blockIdx.z * 256 * (size_t)N;
  const int tid = threadIdx.x;

  if (i0 == i1) {            // empty K-range (block-uniform): zero-fill tile
    for (int e = tid; e < 128 * 64; e += 256)
      po[(size_t)(m0 + (e >> 6)) * N + n0 + (e & 63)] = 0.f;
    return;
  }
  const int kbeg = i0 * 64, kend = i1 * 64;

  const int lane = tid & 63, wave = tid >> 6;
  const int l15  = lane & 15, quad = lane >> 4;
  const int wm0  = (wave & 1) * 64, wn0 = (wave >> 1) * 32;

  const int cg = tid & 7;    // 8-elem column group
  const int rw = tid >> 3;   // row 0..31

  float4 av[4][2];           // A fp32 path: 4 rows x 8 floats
  int4   ab[4];              // A bf16 path: 4 rows x 8 bf16
  float4 wv[2][2];           // W: 2 rows x 8 floats

  auto loadG = [&](int kt) {
    if constexpr (ABF16) {
      const unsigned short* ap =
          (const unsigned short*)Av + (size_t)(m0 + rw) * K + kt + cg * 8;
#pragma unroll
      for (int i = 0; i < 4; ++i)
        ab[i] = *(const int4*)(ap + (size_t)i * 32 * K);
    } else {
      const float* ap = (const float*)Av + (size_t)(m0 + rw) * K + kt + cg * 8;
#pragma unroll
      for (int i = 0; i < 4; ++i) {
        av[i][0] = *(const float4*)(ap + (size_t)i * 32 * K);
        av[i][1] = *(const float4*)(ap + (size_t)i * 32 * K + 4);
      }
    }
#pragma unroll
    for (int i = 0; i < 2; ++i) {
      const float* wp = W + (size_t)(kt + i * 32 + rw) * N + n0 + cg * 8;
      wv[i][0] = *(const float4*)wp;
      wv[i][1] = *(const float4*)(wp + 4);
    }
  };

  auto storeLDS = [&]() {
    if constexpr (ABF16) {
#pragma unroll
      for (int i = 0; i < 4; ++i)    // already bf16: straight b128 copy
        *(int4*)(&Xs[(rw + i * 32) * 72 + cg * 8]) = ab[i];
    } else {
#pragma unroll
      for (int i = 0; i < 4; ++i) {  // convert + one b128 write per row
        union { unsigned short u[8]; int4 v; } t;
        const float* f = (const float*)&av[i][0];
#pragma unroll
        for (int j = 0; j < 8; ++j) t.u[j] = f2bf(f[j]);
        *(int4*)(&Xs[(rw + i * 32) * 72 + cg * 8]) = t.v;
      }
    }
#pragma unroll
    for (int i = 0; i < 2; ++i) {    // W: transpose+convert scatter
      const int r = i * 32 + rw;
      const float* f = (const float*)&wv[i][0];
#pragma unroll
      for (int j = 0; j < 8; ++j)
        Ws[(cg * 8 + j) * 72 + (r ^ (cg << 3))] = f2bf(f[j]);
    }
  };

  f32x4 acc[4][2];
#pragma unroll
  for (int mi = 0; mi < 4; ++mi)
#pragma unroll
    for (int ni = 0; ni < 2; ++ni)
      acc[mi][ni] = (f32x4){0.f, 0.f, 0.f, 0.f};

  loadG(kbeg);
  for (int kt = kbeg; kt < kend; kt += 64) {
    __syncthreads();                        // prior tile's LDS reads done
    storeLDS();
    if (kt + 64 < kend) loadG(kt + 64);     // prefetch: overlaps barrier+MFMA
    __syncthreads();                        // stores visible
#pragma unroll
    for (int kk = 0; kk < 64; kk += 32) {
      bf16x8 af[4], bf[2];
#pragma unroll
      for (int mi = 0; mi < 4; ++mi)
        af[mi] = *(const bf16x8*)(&Xs[(wm0 + mi * 16 + l15) * 72 + kk + quad * 8]);
#pragma unroll
      for (int ni = 0; ni < 2; ++ni) {
        const int n_l = wn0 + ni * 16 + l15;
        bf[ni] = *(const bf16x8*)(&Ws[n_l * 72 + ((kk + quad * 8) ^ ((n_l >> 3) << 3))]);
      }
#pragma unroll
      for (int mi = 0; mi < 4; ++mi)
#pragma unroll
        for (int ni = 0; ni < 2; ++ni)
          acc[mi][ni] = __builtin_amdgcn_mfma_f32_16x16x32_bf16(
              af[mi], bf[ni], acc[mi][ni], 0, 0, 0);
    }
  }

  // epilogue: C/D layout col=lane&15, row=quad*4+reg; plain coalesced stores
#pragma unroll
  for (int mi = 0; mi < 4; ++mi) {
#pragma unroll
    for (int ni = 0; ni < 2; ++ni) {
      const int n_out = n0 + wn0 + ni * 16 + l15;
#pragma unroll
      for (int r = 0; r < 4; ++r) {
        const int m_out = m0 + wm0 + mi * 16 + quad * 4 + r;
        po[(size_t)m_out * N + n_out] = acc[mi][ni][r];
      }
    }
  }
}

extern "C" void kernel_launch(void* const* d_in, const int* in_sizes, int n_in,
                              void* d_out, int out_size, void* d_ws, size_t ws_size,
                              hipStream_t stream) {
  const float* x  = (const float*)d_in[0];  // [256,64,64] fp32
  const float* W1 = (const float*)d_in[1];  // [4096,8192] fp32
  const float* b1 = (const float*)d_in[2];  // [8192] fp32
  const float* W2 = (const float*)d_in[3];  // [8192,4096] fp32
  const float* b2 = (const float*)d_in[4];  // [4096] fp32
  // d_in[5] = seq_len; dims hardcoded: B=256, S=64, I=64, H=128, O=64

  // workspace layout (68 MB total):
  float* Hp = (float*)d_ws;                          // [4][256][8192] fp32, 32 MB
  unsigned short* Hbf = (unsigned short*)(Hp + (size_t)4 * 2097152);  // [256][8192] bf16, 4 MB
  float* Op = (float*)(Hbf + 2097152);               // [8][256][4096] fp32, 32 MB
  float* out = (float*)d_out;                        // [256,4096] fp32

  // GEMM1: x[256,4096] @ W1[4096,8192], mask 64(K) x 128(N), split-K x4 -> partials
  gemm_sk<64, 128, 4, false><<<dim3(128, 2, 4), 256, 0, stream>>>(
      x, W1, Hp, 4096, 8192);

  // H = bf16(relu(sum_z Hp + b1))
  reduce1_relu_bf16<<<dim3(2048), 256, 0, stream>>>(Hp, b1, Hbf);

  // GEMM2: H[256,8192](bf16) @ W2[8192,4096], mask 128(K) x 64(N), split-K x8 -> partials
  gemm_sk<128, 64, 8, true><<<dim3(64, 2, 8), 256, 0, stream>>>(
      Hbf, W2, Op, 8192, 4096);

  // out = sum_z Op + b2
  reduce2_bias<<<dim3(1024), 256, 0, stream>>>(Op, b2, out);
}